// Round 1
// baseline (253.338 us; speedup 1.0000x reference)
//
#include <hip/hip_runtime.h>

// GlobalAttentionPooling: tensor_square_0e -> selu -> @W -> segment softmax -> weighted segment sum
// N nodes, 80 f32 ft (32 scalar + 16 x 3-vec), NG=1024 graphs (sorted batch_index), F=664.
//
// Math identities (validated rounds 1-4, absmax 3.9e-3):
//   selu const term cancels in softmax; pre-scale s by sqrt(log2e), v by sqrt(log2e/sqrt3)
//   so pair products are f*log2e -> exp2 directly. out_g = (sum nf*ex)/z_g.
//
// Round-6 change (occupancy):
//   Round-5 counters: main_kernel 88us, VALUBusy 35%, Occupancy 36%, HBM 20% -> latency-bound,
//   grid-starved: 938 blocks x 5 waves = 4.6 waves/SIMD; issue-demand arithmetic says ~20us of
//   real work. Fix: split each node's phase-1 triangle across a LANE PAIR by parity of row i
//   (scalar 136/136 f2-iters, vector 36/36 -- exactly balanced; W zero-padding already covers
//   j<i slots). One __shfl_xor(.,1) per accumulator recombines. Block stays 320 threads but
//   owns only 160 nodes -> grid 1875, 9375 waves (~9.2/SIMD demand), launch_bounds(320,8)
//   caps VGPR at 64 (compiler used 36 under a 256 cap -> no spill risk).

typedef float f2 __attribute__((ext_vector_type(2)));

#define C0 32
#define C1 16
#define NODE_F 80
#define NG_CONST 1024
#define NPB 160                 // nodes per block
#define TPB 320                 // threads per block (2 lanes per node)

#define SELU_SCALE 1.0507009873554804934193349852946
#define SELU_ALPHA 1.6732632423543772848170429916717
#define LOG2E      1.4426950408889634073599246810019

#define CS_SCALE 1.2011224087864498f    // sqrt(log2e)
#define CV_SCALE 0.91271231102878545f   // sqrt(log2e/sqrt(3))

// ws float layout:
//   [0, 81920)        S accum: [1024 graphs][80 ch]
//   [81920, 82944)    z accum: [1024]
//   [82944, 84224)    Wpad: 512 f2 scalar-part rows (32x16) then 128 f2 vec-part rows (16x8)
#define WS_S 0
#define WS_Z 81920
#define WS_W 82944

__device__ __forceinline__ int ks_idx(int i, int j) { return i * C0 - (i * (i - 1)) / 2 + (j - i); }
__device__ __forceinline__ int kv_idx(int i, int j) { return 528 + i * C1 - (i * (i - 1)) / 2 + (j - i); }

// zero the accumulators + build padded W tables
__global__ __launch_bounds__(256) void prep_kernel(
    const float* __restrict__ W, float* __restrict__ ws)
{
    const int t = blockIdx.x * blockDim.x + threadIdx.x;
    if (t < 82944) {
        ws[t] = 0.0f;                       // S and z
    } else {
        int u = t - 82944;
        if (u < 512) {                      // Ws: i in [0,32), q in [0,16)
            int i = u >> 4, q = u & 15;
            int j0 = 2 * q, j1 = 2 * q + 1;
            ws[WS_W + 2 * u]     = (j0 >= i) ? W[ks_idx(i, j0)] : 0.0f;
            ws[WS_W + 2 * u + 1] = (j1 >= i) ? W[ks_idx(i, j1)] : 0.0f;
        } else if (u < 640) {               // Wv: i in [0,16), q in [0,8)
            int v = u - 512;
            int i = v >> 3, q = v & 7;
            int j0 = 2 * q, j1 = 2 * q + 1;
            ws[WS_W + 1024 + 2 * v]     = (j0 >= i) ? W[kv_idx(i, j0)] : 0.0f;
            ws[WS_W + 1024 + 2 * v + 1] = (j1 >= i) ? W[kv_idx(i, j1)] : 0.0f;
        }
    }
}

__global__ __launch_bounds__(TPB, 8) void main_kernel(
    const float* __restrict__ nf, const int* __restrict__ bi,
    const float* __restrict__ ws, float* __restrict__ S,
    float* __restrict__ z, int N)
{
    __shared__ __align__(16) float Wlds[1280];
    __shared__ float exl[NPB];
    __shared__ int   bil[NPB];

    const int tid  = threadIdx.x;
    const int base = blockIdx.x * NPB;
    const float4* g4 = (const float4*)nf;

    #pragma unroll
    for (int u = tid; u < 1280; u += TPB) Wlds[u] = ws[WS_W + u];

    if (tid < NPB) {
        int idx = base + tid;
        bil[tid] = bi[idx > N - 1 ? N - 1 : idx];
    }

    const int  ln    = tid >> 1;            // local node 0..159
    const int  p     = tid & 1;             // parity: which half of the triangle rows
    const int  n     = base + ln;
    const bool valid = (n < N);
    const int  nn    = valid ? n : (N - 1);
    __syncthreads();                        // Wlds + bil ready

    // ---- phase 1: lane pair shares one node; lane p does rows i with (i&1)==p ----
    float4 row4[20];
    #pragma unroll
    for (int q = 0; q < 20; ++q) row4[q] = g4[(size_t)nn * 20 + q];
    const float* row = (const float*)row4;

    const f2* WsL = (const f2*)Wlds;          // 512 f2
    const f2* WvL = (const f2*)(Wlds + 1024); // 128 f2

    f2 accA[2], accB[2];
    accA[0] = (f2)0.f; accA[1] = (f2)0.f; accB[0] = (f2)0.f; accB[1] = (f2)0.f;

    {   // scalar part: lane handles i = 2k+p, k=0..15 (136 f2-iters per lane)
        f2 s2[C0 / 2];
        #pragma unroll
        for (int q = 0; q < C0 / 2; ++q)
            s2[q] = f2{row[2 * q], row[2 * q + 1]} * CS_SCALE;
        #pragma unroll
        for (int k = 0; k < C0 / 2; ++k) {
            const int i = 2 * k + p;                    // lane-dependent row
            const float si = p ? s2[k].y : s2[k].x;
            const f2 si2 = f2{si, si};
            #pragma unroll
            for (int q = k; q < C0 / 2; ++q) {
                f2 f = si2 * s2[q];
                f2 pp = __builtin_elementwise_max(f, (f2)0.f);
                f2 m  = __builtin_elementwise_min(f, (f2)0.f);
                f2 e; e.x = __builtin_amdgcn_exp2f(m.x);
                      e.y = __builtin_amdgcn_exp2f(m.y);
                f2 w = WsL[i * 16 + q];             // 2 addrs/wave, 128B apart: 2-way = free
                accA[q & 1] = __builtin_elementwise_fma(w, pp, accA[q & 1]);
                accB[q & 1] = __builtin_elementwise_fma(w, e, accB[q & 1]);
            }
        }
    }
    {   // vector part: lane handles i = 2k+p, k=0..7 (36 f2-iters per lane)
        f2 vp[C1 / 2][3];
        #pragma unroll
        for (int q = 0; q < C1 / 2; ++q) {
            #pragma unroll
            for (int c = 0; c < 3; ++c)
                vp[q][c] = f2{row[C0 + 6 * q + c], row[C0 + 6 * q + 3 + c]} * CV_SCALE;
        }
        #pragma unroll
        for (int k = 0; k < C1 / 2; ++k) {
            const int i = 2 * k + p;
            const float vi0 = p ? vp[k][0].y : vp[k][0].x;
            const float vi1 = p ? vp[k][1].y : vp[k][1].x;
            const float vi2 = p ? vp[k][2].y : vp[k][2].x;
            #pragma unroll
            for (int q = k; q < C1 / 2; ++q) {
                f2 f = vp[q][0] * f2{vi0, vi0};
                f = __builtin_elementwise_fma(vp[q][1], f2{vi1, vi1}, f);
                f = __builtin_elementwise_fma(vp[q][2], f2{vi2, vi2}, f);
                f2 pp = __builtin_elementwise_max(f, (f2)0.f);
                f2 m  = __builtin_elementwise_min(f, (f2)0.f);
                f2 e; e.x = __builtin_amdgcn_exp2f(m.x);
                      e.y = __builtin_amdgcn_exp2f(m.y);
                f2 w = WvL[i * 8 + q];
                accA[q & 1] = __builtin_elementwise_fma(w, pp, accA[q & 1]);
                accB[q & 1] = __builtin_elementwise_fma(w, e, accB[q & 1]);
            }
        }
    }

    float A1 = accA[0].x + accA[0].y + accA[1].x + accA[1].y;
    float A2 = accB[0].x + accB[0].y + accB[1].x + accB[1].y;
    A1 += __shfl_xor(A1, 1);                // combine lane-pair halves
    A2 += __shfl_xor(A2, 1);
    const float l2 = fmaf((float)SELU_SCALE, A1,
                          (float)(SELU_SCALE * SELU_ALPHA * LOG2E) * A2);
    if (p == 0) exl[ln] = valid ? __builtin_amdgcn_exp2f(l2) : 0.0f;
    __syncthreads();

    // ---- phase 2: thread (no, c4) sums 10 contiguous nodes' channel-group, flush per graph run ----
    const int no = tid / 20;       // 0..15
    const int c4 = tid % 20;
    const int nb = no * 10;
    int cg = bil[nb];
    float4 acc = make_float4(0.f, 0.f, 0.f, 0.f);
    float  zacc = 0.0f;

    #pragma unroll
    for (int k = 0; k < 10; ++k) {
        const int nl = nb + k;
        const int g2 = bil[nl];
        if (g2 != cg) {
            unsafeAtomicAdd(&S[cg * NODE_F + c4 * 4 + 0], acc.x);
            unsafeAtomicAdd(&S[cg * NODE_F + c4 * 4 + 1], acc.y);
            unsafeAtomicAdd(&S[cg * NODE_F + c4 * 4 + 2], acc.z);
            unsafeAtomicAdd(&S[cg * NODE_F + c4 * 4 + 3], acc.w);
            if (c4 == 0) unsafeAtomicAdd(&z[cg], zacc);
            acc = make_float4(0.f, 0.f, 0.f, 0.f); zacc = 0.0f; cg = g2;
        }
        int idx = base + nl; if (idx > N - 1) idx = N - 1;   // pad nodes have w=0
        const float  w = exl[nl];
        const float4 v = g4[(size_t)idx * 20 + c4];
        acc.x = fmaf(v.x, w, acc.x); acc.y = fmaf(v.y, w, acc.y);
        acc.z = fmaf(v.z, w, acc.z); acc.w = fmaf(v.w, w, acc.w);
        zacc += w;
    }
    unsafeAtomicAdd(&S[cg * NODE_F + c4 * 4 + 0], acc.x);
    unsafeAtomicAdd(&S[cg * NODE_F + c4 * 4 + 1], acc.y);
    unsafeAtomicAdd(&S[cg * NODE_F + c4 * 4 + 2], acc.z);
    unsafeAtomicAdd(&S[cg * NODE_F + c4 * 4 + 3], acc.w);
    if (c4 == 0) unsafeAtomicAdd(&z[cg], zacc);
}

__global__ __launch_bounds__(256) void divide_kernel(
    const float* __restrict__ S, const float* __restrict__ z,
    float* __restrict__ out)
{
    const int t = blockIdx.x * blockDim.x + threadIdx.x;
    if (t >= NG_CONST * NODE_F) return;
    const float zz = z[t / NODE_F];
    out[t] = (zz > 0.0f) ? (S[t] / zz) : 0.0f;
}

extern "C" void kernel_launch(void* const* d_in, const int* in_sizes, int n_in,
                              void* d_out, int out_size, void* d_ws, size_t ws_size,
                              hipStream_t stream) {
    const float* nf = (const float*)d_in[0];   // (N, 80) f32
    const int*   bi = (const int*)d_in[1];     // (N,) i32 sorted
    // d_in[2] = num_graphs (static 1024)
    const float* W  = (const float*)d_in[3];   // (664,) f32
    float* out = (float*)d_out;

    const int N = in_sizes[0] / NODE_F;
    float* ws = (float*)d_ws;
    float* S  = ws + WS_S;
    float* z  = ws + WS_Z;

    hipLaunchKernelGGL(prep_kernel, dim3(332), dim3(256), 0, stream, W, ws);
    hipLaunchKernelGGL(main_kernel, dim3((N + NPB - 1) / NPB), dim3(TPB), 0, stream,
                       nf, bi, ws, S, z, N);
    hipLaunchKernelGGL(divide_kernel, dim3((NG_CONST * NODE_F + 255) / 256), dim3(256),
                       0, stream, S, z, out);
}

// Round 2
// 211.618 us; speedup vs baseline: 1.1971x; 1.1971x over previous
//
#include <hip/hip_runtime.h>

// GlobalAttentionPooling: tensor_square_0e -> selu -> @W -> segment softmax -> weighted segment sum
// N nodes, 80 f32 ft (32 scalar + 16 x 3-vec), NG=1024 graphs (sorted batch_index), F=664.
//
// Math identities (validated rounds 1-4, absmax 3.9e-3):
//   selu const term cancels in softmax; pre-scale s by sqrt(log2e), v by sqrt(log2e/sqrt3)
//   so pair products are f*log2e -> exp2 directly. out_g = (sum nf*ex)/z_g.
//
// Round-7: revert round-6 pair-split (it doubled atomic flush count -> WRITE 20->136MB,
//   added 2.4M LDS conflicts, 88->148us). Keep round-5 structure (1 thread/node, NPB=320).
//   New: hand software-pipelining of phase 1. Round-5 VGPR=36 showed the compiler kept a
//   minimal rolling window (exp2 + ds latency exposed every iter; VALUBusy 35%, 4.4x over
//   issue floor). Per row: stage ds_reads -> pure-reg mul/min/exp2 stream (16 exps
//   back-to-back hide their own latency) -> fma stage. Vector-half global loads issued
//   mid-triangle so HBM latency hides under rows 16..31.

typedef float f2 __attribute__((ext_vector_type(2)));

#define C0 32
#define C1 16
#define NODE_F 80
#define NG_CONST 1024
#define NPB 320                 // nodes per block == threads per block (1 thread/node)
#define TPB 320

#define SELU_SCALE 1.0507009873554804934193349852946
#define SELU_ALPHA 1.6732632423543772848170429916717
#define LOG2E      1.4426950408889634073599246810019

#define CS_SCALE 1.2011224087864498f    // sqrt(log2e)
#define CV_SCALE 0.91271231102878545f   // sqrt(log2e/sqrt(3))

// ws float layout:
//   [0, 81920)        S accum: [1024 graphs][80 ch]
//   [81920, 82944)    z accum: [1024]
//   [82944, 84224)    Wpad: 512 f2 scalar-part rows (32x16) then 128 f2 vec-part rows (16x8)
#define WS_S 0
#define WS_Z 81920
#define WS_W 82944

__device__ __forceinline__ int ks_idx(int i, int j) { return i * C0 - (i * (i - 1)) / 2 + (j - i); }
__device__ __forceinline__ int kv_idx(int i, int j) { return 528 + i * C1 - (i * (i - 1)) / 2 + (j - i); }

// zero the accumulators + build padded W tables
__global__ __launch_bounds__(256) void prep_kernel(
    const float* __restrict__ W, float* __restrict__ ws)
{
    const int t = blockIdx.x * blockDim.x + threadIdx.x;
    if (t < 82944) {
        ws[t] = 0.0f;                       // S and z
    } else {
        int u = t - 82944;
        if (u < 512) {                      // Ws: i in [0,32), q in [0,16)
            int i = u >> 4, q = u & 15;
            int j0 = 2 * q, j1 = 2 * q + 1;
            ws[WS_W + 2 * u]     = (j0 >= i) ? W[ks_idx(i, j0)] : 0.0f;
            ws[WS_W + 2 * u + 1] = (j1 >= i) ? W[ks_idx(i, j1)] : 0.0f;
        } else if (u < 640) {               // Wv: i in [0,16), q in [0,8)
            int v = u - 512;
            int i = v >> 3, q = v & 7;
            int j0 = 2 * q, j1 = 2 * q + 1;
            ws[WS_W + 1024 + 2 * v]     = (j0 >= i) ? W[kv_idx(i, j0)] : 0.0f;
            ws[WS_W + 1024 + 2 * v + 1] = (j1 >= i) ? W[kv_idx(i, j1)] : 0.0f;
        }
    }
}

__global__ __launch_bounds__(TPB, 2) void main_kernel(
    const float* __restrict__ nf, const int* __restrict__ bi,
    const float* __restrict__ ws, float* __restrict__ S,
    float* __restrict__ z, int N)
{
    __shared__ __align__(16) float Wlds[1280];
    __shared__ float exl[NPB];
    __shared__ int   bil[NPB];

    const int tid  = threadIdx.x;
    const int base = blockIdx.x * NPB;
    const float4* g4 = (const float4*)nf;

    #pragma unroll
    for (int u = tid; u < 1280; u += TPB) Wlds[u] = ws[WS_W + u];

    const int  n     = base + tid;
    const bool valid = (n < N);
    const int  nn    = valid ? n : (N - 1);
    bil[tid] = bi[nn];
    __syncthreads();                        // Wlds + bil ready

    const float4* gp = g4 + (size_t)nn * 20;
    const f2* WsL = (const f2*)Wlds;          // 512 f2
    const f2* WvL = (const f2*)(Wlds + 1024); // 128 f2

    // ---- phase 1: per-thread row, staged pipeline ----
    // scalar half of the row first
    float4 rs[8];
    #pragma unroll
    for (int q = 0; q < 8; ++q) rs[q] = gp[q];

    f2 s2[16];
    #pragma unroll
    for (int q = 0; q < 8; ++q) {
        s2[2 * q]     = f2{rs[q].x, rs[q].y} * CS_SCALE;
        s2[2 * q + 1] = f2{rs[q].z, rs[q].w} * CS_SCALE;
    }

    f2 accA[4], accB[4];
    #pragma unroll
    for (int j = 0; j < 4; ++j) { accA[j] = (f2)0.f; accB[j] = (f2)0.f; }

    // rows 0..15: two chunks of <=8 f2 each; stage {w-loads | mul/min/exp2 | fma}
    #pragma unroll
    for (int i = 0; i < 16; ++i) {
        const int k = i >> 1;
        const float si = (i & 1) ? s2[k].y : s2[k].x;
        const f2 si2 = f2{si, si};
        #pragma unroll
        for (int c = k; c < 16; c += 8) {
            const int ce = (c + 8 < 16) ? (c + 8) : 16;
            f2 wq[8], ff[8], ee[8];
            #pragma unroll
            for (int q = c; q < ce; ++q) wq[q - c] = WsL[i * 16 + q];   // broadcast ds_read_b64
            #pragma unroll
            for (int q = c; q < ce; ++q) {                              // pure-register stream
                f2 f = si2 * s2[q];
                ff[q - c] = f;
                f2 m = __builtin_elementwise_min(f, (f2)0.f);
                ee[q - c].x = __builtin_amdgcn_exp2f(m.x);
                ee[q - c].y = __builtin_amdgcn_exp2f(m.y);
            }
            #pragma unroll
            for (int q = c; q < ce; ++q) {                              // consume w + e
                f2 p = __builtin_elementwise_max(ff[q - c], (f2)0.f);
                accA[q & 3] = __builtin_elementwise_fma(wq[q - c], p, accA[q & 3]);
                accB[q & 3] = __builtin_elementwise_fma(wq[q - c], ee[q - c], accB[q & 3]);
            }
        }
    }

    // issue vector-half global loads now; rows 16..31 cover their HBM latency
    float4 rv[12];
    #pragma unroll
    for (int q = 0; q < 12; ++q) rv[q] = gp[8 + q];

    // rows 16..31: single chunk (<=8 f2)
    #pragma unroll
    for (int i = 16; i < 32; ++i) {
        const int k = i >> 1;                   // 8..15
        const float si = (i & 1) ? s2[k].y : s2[k].x;
        const f2 si2 = f2{si, si};
        f2 wq[8], ff[8], ee[8];
        #pragma unroll
        for (int q = k; q < 16; ++q) wq[q - k] = WsL[i * 16 + q];
        #pragma unroll
        for (int q = k; q < 16; ++q) {
            f2 f = si2 * s2[q];
            ff[q - k] = f;
            f2 m = __builtin_elementwise_min(f, (f2)0.f);
            ee[q - k].x = __builtin_amdgcn_exp2f(m.x);
            ee[q - k].y = __builtin_amdgcn_exp2f(m.y);
        }
        #pragma unroll
        for (int q = k; q < 16; ++q) {
            f2 p = __builtin_elementwise_max(ff[q - k], (f2)0.f);
            accA[q & 3] = __builtin_elementwise_fma(wq[q - k], p, accA[q & 3]);
            accB[q & 3] = __builtin_elementwise_fma(wq[q - k], ee[q - k], accB[q & 3]);
        }
    }

    // vector part: build vp from rv, then staged rows
    const float* rvf = (const float*)rv;
    f2 vp[8][3];
    #pragma unroll
    for (int q = 0; q < 8; ++q) {
        #pragma unroll
        for (int c3 = 0; c3 < 3; ++c3)
            vp[q][c3] = f2{rvf[6 * q + c3], rvf[6 * q + 3 + c3]} * CV_SCALE;
    }

    #pragma unroll
    for (int i = 0; i < C1; ++i) {
        const int k = i >> 1;
        const float vi0 = (i & 1) ? vp[k][0].y : vp[k][0].x;
        const float vi1 = (i & 1) ? vp[k][1].y : vp[k][1].x;
        const float vi2 = (i & 1) ? vp[k][2].y : vp[k][2].x;
        f2 wq[8], ff[8], ee[8];
        #pragma unroll
        for (int q = k; q < 8; ++q) wq[q - k] = WvL[i * 8 + q];
        #pragma unroll
        for (int q = k; q < 8; ++q) {
            f2 f = vp[q][0] * f2{vi0, vi0};
            f = __builtin_elementwise_fma(vp[q][1], f2{vi1, vi1}, f);
            f = __builtin_elementwise_fma(vp[q][2], f2{vi2, vi2}, f);
            ff[q - k] = f;
            f2 m = __builtin_elementwise_min(f, (f2)0.f);
            ee[q - k].x = __builtin_amdgcn_exp2f(m.x);
            ee[q - k].y = __builtin_amdgcn_exp2f(m.y);
        }
        #pragma unroll
        for (int q = k; q < 8; ++q) {
            f2 p = __builtin_elementwise_max(ff[q - k], (f2)0.f);
            accA[q & 3] = __builtin_elementwise_fma(wq[q - k], p, accA[q & 3]);
            accB[q & 3] = __builtin_elementwise_fma(wq[q - k], ee[q - k], accB[q & 3]);
        }
    }

    const float A1 = (accA[0].x + accA[0].y) + (accA[1].x + accA[1].y)
                   + (accA[2].x + accA[2].y) + (accA[3].x + accA[3].y);
    const float A2 = (accB[0].x + accB[0].y) + (accB[1].x + accB[1].y)
                   + (accB[2].x + accB[2].y) + (accB[3].x + accB[3].y);
    const float l2 = fmaf((float)SELU_SCALE, A1,
                          (float)(SELU_SCALE * SELU_ALPHA * LOG2E) * A2);
    exl[tid] = valid ? __builtin_amdgcn_exp2f(l2) : 0.0f;
    __syncthreads();

    // ---- phase 2: thread (no, c4) sums 20 contiguous nodes' channel-group, flush per graph run ----
    const int no = tid / 20;       // 0..15
    const int c4 = tid % 20;
    int cg = bil[no * 20];
    float4 acc = make_float4(0.f, 0.f, 0.f, 0.f);
    float  zacc = 0.0f;

    #pragma unroll
    for (int k = 0; k < 20; ++k) {
        const int nl = no * 20 + k;
        const int g2 = bil[nl];
        if (g2 != cg) {
            unsafeAtomicAdd(&S[cg * NODE_F + c4 * 4 + 0], acc.x);
            unsafeAtomicAdd(&S[cg * NODE_F + c4 * 4 + 1], acc.y);
            unsafeAtomicAdd(&S[cg * NODE_F + c4 * 4 + 2], acc.z);
            unsafeAtomicAdd(&S[cg * NODE_F + c4 * 4 + 3], acc.w);
            if (c4 == 0) unsafeAtomicAdd(&z[cg], zacc);
            acc = make_float4(0.f, 0.f, 0.f, 0.f); zacc = 0.0f; cg = g2;
        }
        int idx = base + nl; if (idx > N - 1) idx = N - 1;   // pad nodes have w=0
        const float  w = exl[nl];
        const float4 v = g4[(size_t)idx * 20 + c4];
        acc.x = fmaf(v.x, w, acc.x); acc.y = fmaf(v.y, w, acc.y);
        acc.z = fmaf(v.z, w, acc.z); acc.w = fmaf(v.w, w, acc.w);
        zacc += w;
    }
    unsafeAtomicAdd(&S[cg * NODE_F + c4 * 4 + 0], acc.x);
    unsafeAtomicAdd(&S[cg * NODE_F + c4 * 4 + 1], acc.y);
    unsafeAtomicAdd(&S[cg * NODE_F + c4 * 4 + 2], acc.z);
    unsafeAtomicAdd(&S[cg * NODE_F + c4 * 4 + 3], acc.w);
    if (c4 == 0) unsafeAtomicAdd(&z[cg], zacc);
}

__global__ __launch_bounds__(256) void divide_kernel(
    const float* __restrict__ S, const float* __restrict__ z,
    float* __restrict__ out)
{
    const int t = blockIdx.x * blockDim.x + threadIdx.x;
    if (t >= NG_CONST * NODE_F) return;
    const float zz = z[t / NODE_F];
    out[t] = (zz > 0.0f) ? (S[t] / zz) : 0.0f;
}

extern "C" void kernel_launch(void* const* d_in, const int* in_sizes, int n_in,
                              void* d_out, int out_size, void* d_ws, size_t ws_size,
                              hipStream_t stream) {
    const float* nf = (const float*)d_in[0];   // (N, 80) f32
    const int*   bi = (const int*)d_in[1];     // (N,) i32 sorted
    // d_in[2] = num_graphs (static 1024)
    const float* W  = (const float*)d_in[3];   // (664,) f32
    float* out = (float*)d_out;

    const int N = in_sizes[0] / NODE_F;
    float* ws = (float*)d_ws;
    float* S  = ws + WS_S;
    float* z  = ws + WS_Z;

    hipLaunchKernelGGL(prep_kernel, dim3(332), dim3(256), 0, stream, W, ws);
    hipLaunchKernelGGL(main_kernel, dim3((N + NPB - 1) / NPB), dim3(TPB), 0, stream,
                       nf, bi, ws, S, z, N);
    hipLaunchKernelGGL(divide_kernel, dim3((NG_CONST * NODE_F + 255) / 256), dim3(256),
                       0, stream, S, z, out);
}